// Round 11
// baseline (35.511 us; speedup 1.0000x reference)
//
#include <hip/hip_runtime.h>
#include <math.h>

#define NPT 512
#define BROWS 4096
#define TAB_U4 9    // 9 uint4 slots per lane, SoA: tab[slot*64 + lane]

typedef _Float16 half8 __attribute__((ext_vector_type(8)));
typedef _Float16 half4 __attribute__((ext_vector_type(4)));
typedef _Float16 h2    __attribute__((ext_vector_type(2)));
typedef float    f32x4 __attribute__((ext_vector_type(4)));
typedef unsigned int u32x4 __attribute__((ext_vector_type(4)));

__device__ __forceinline__ float sigmoidf_fast(float x) {
    return 1.0f / (1.0f + __expf(-x));
}

// cvt_pkrtz returns __fp16x2; bit-cast to our h2 (_Float16x2) — same bits.
__device__ __forceinline__ h2 pkrtz(float a, float b) {
    return __builtin_bit_cast(h2, __builtin_amdgcn_cvt_pkrtz(a, b));
}

#if __has_builtin(__builtin_amdgcn_fdot2)
__device__ __forceinline__ float fdot2(h2 a, h2 b, float c) {
    return __builtin_amdgcn_fdot2(__builtin_bit_cast(__fp16 __attribute__((ext_vector_type(2))), a),
                                  __builtin_bit_cast(__fp16 __attribute__((ext_vector_type(2))), b),
                                  c, false);
}
#else
__device__ __forceinline__ float fdot2(h2 a, h2 b, float c) {
    c = fmaf((float)a[0], (float)b[0], c);
    c = fmaf((float)a[1], (float)b[1], c);
    return c;
}
#endif

// K=16 f16 MFMA; fallback emulates exactly via K=32 with disjoint zero-padded
// k-embedding (lane j0..3 -> k=kg*8+j, zeros j4..7 on both operands).
#if __has_builtin(__builtin_amdgcn_mfma_f32_16x16x16f16)
__device__ __forceinline__ f32x4 mfma16(half4 a, half4 b, f32x4 c) {
    return __builtin_amdgcn_mfma_f32_16x16x16f16(a, b, c, 0, 0, 0);
}
#else
__device__ __forceinline__ f32x4 mfma16(half4 a, half4 b, f32x4 c) {
    half8 a8 = {a[0], a[1], a[2], a[3],
                (_Float16)0.f, (_Float16)0.f, (_Float16)0.f, (_Float16)0.f};
    half8 b8 = {b[0], b[1], b[2], b[3],
                (_Float16)0.f, (_Float16)0.f, (_Float16)0.f, (_Float16)0.f};
    return __builtin_amdgcn_mfma_f32_16x16x32_f16(a8, b8, c, 0, 0, 0);
}
#endif

union H4 { half4 v; h2 p[2]; unsigned int w[2]; };

// ---------------- setup: per-lane constant table (1 wave) ----------------
// slot0: A1 tiles 0,1   slot1: A1 tiles 2,3        (layer-1 A = W1^T + bias row)
// slot2: A2[m0][s0,s1]  slot3: A2[m0][s2,s3]       (layer-2 A = W2^T)
// slot4: A2[m1][s0,s1]  slot5: A2[m1][s2,s3]
// slot6: accInit0(b2)   slot7: accInit1(b2)   slot8: w3 packed pairs
__global__ __launch_bounds__(64) void setup_kernel(
    const float* __restrict__ W1, const float* __restrict__ b1,
    const float* __restrict__ W2, const float* __restrict__ b2,
    const float* __restrict__ W3, u32x4* __restrict__ tab)
{
    const int lane = threadIdx.x & 63;
    const int nn   = lane & 15;
    const int kg   = lane >> 4;

    // A1[t]: lane holds A[row = t*16+nn][k = kg*4+j], j=0..3, where
    // k 0..3 = W1 rows, k4 = b1 (bias, paired with B k4 = 1.0), k>=5 zero.
    unsigned int a1w[8];
    #pragma unroll
    for (int t = 0; t < 4; ++t) {
        const int ch = t * 16 + nn;
        h2 j01, j23;
        j01[0] = (_Float16)0.f; j01[1] = (_Float16)0.f;
        j23[0] = (_Float16)0.f; j23[1] = (_Float16)0.f;
        if (kg == 0) {
            j01[0] = (_Float16)W1[0 * 64 + ch]; j01[1] = (_Float16)W1[1 * 64 + ch];
            j23[0] = (_Float16)W1[2 * 64 + ch]; j23[1] = (_Float16)W1[3 * 64 + ch];
        } else if (kg == 1) {
            j01[0] = (_Float16)b1[ch];          // k = 4
        }
        a1w[t * 2 + 0] = __builtin_bit_cast(unsigned int, j01);
        a1w[t * 2 + 1] = __builtin_bit_cast(unsigned int, j23);
    }
    {
        u32x4 v0, v1;
        #pragma unroll
        for (int e = 0; e < 4; ++e) { v0[e] = a1w[e]; v1[e] = a1w[4 + e]; }
        tab[0 * 64 + lane] = v0;
        tab[1 * 64 + lane] = v1;
    }

    // A2[m][s]: lane holds A[row = m*16+nn][k = kg*4+j] = W2[s*16+kg*4+j][m*16+nn]
    #pragma unroll
    for (int m = 0; m < 2; ++m) {
        unsigned int a2w[8];
        #pragma unroll
        for (int s = 0; s < 4; ++s) {
            const int bc  = s * 16 + kg * 4;
            const int col = m * 16 + nn;
            h2 j01, j23;
            j01[0] = (_Float16)W2[(bc + 0) * 32 + col];
            j01[1] = (_Float16)W2[(bc + 1) * 32 + col];
            j23[0] = (_Float16)W2[(bc + 2) * 32 + col];
            j23[1] = (_Float16)W2[(bc + 3) * 32 + col];
            a2w[s * 2 + 0] = __builtin_bit_cast(unsigned int, j01);
            a2w[s * 2 + 1] = __builtin_bit_cast(unsigned int, j23);
        }
        u32x4 v0, v1;
        #pragma unroll
        for (int e = 0; e < 4; ++e) { v0[e] = a2w[e]; v1[e] = a2w[4 + e]; }
        tab[(2 + m * 2) * 64 + lane] = v0;
        tab[(3 + m * 2) * 64 + lane] = v1;
    }

    f32x4 ai0, ai1;
    #pragma unroll
    for (int r = 0; r < 4; ++r) {
        ai0[r] = b2[kg * 4 + r];
        ai1[r] = b2[16 + kg * 4 + r];
    }
    tab[6 * 64 + lane] = __builtin_bit_cast(u32x4, ai0);
    tab[7 * 64 + lane] = __builtin_bit_cast(u32x4, ai1);

    u32x4 w3v;
    #pragma unroll
    for (int e = 0; e < 2; ++e) {
        h2 a, b;
        a[0] = (_Float16)W3[kg * 4 + 2 * e];
        a[1] = (_Float16)W3[kg * 4 + 2 * e + 1];
        b[0] = (_Float16)W3[16 + kg * 4 + 2 * e];
        b[1] = (_Float16)W3[16 + kg * 4 + 2 * e + 1];
        w3v[e]     = __builtin_bit_cast(unsigned int, a);
        w3v[2 + e] = __builtin_bit_cast(unsigned int, b);
    }
    tab[8 * 64 + lane] = w3v;
}

// ---------------- main: 1 block = 2 rows = 4 waves ----------------
// MLP fully on MFMA: layer1 = 4x mfma16 (bias in K), relu+pack feeds layer2's
// B fragments directly (layout identity), layer2 = 8x mfma16 (C init = b2).
// Epilogue + split-scan are the round-10 verified bodies.
__global__ __launch_bounds__(256, 4) void wps_kernel(
    const float* __restrict__ wp,    // (B, N, 2)
    const float* __restrict__ sww,
    const float* __restrict__ b3,
    const u32x4* __restrict__ tab,
    float* __restrict__ out)
{
    __shared__ float sLg[2][NPT];    // raw logits, 4 KB
    __shared__ float2 sY[2];         // y_255 per row

    const int t    = threadIdx.x;
    const int lane = t & 63;
    const int wv   = t >> 6;
    const int row0 = blockIdx.x * 2;

    const int nn = lane & 15;
    const int kg = lane >> 4;

    // ---- constants from table (9 coalesced dwordx4 loads, ~36 VGPR) ----
    H4 A1[4];
    {
        u32x4 v0 = tab[0 * 64 + lane];
        u32x4 v1 = tab[1 * 64 + lane];
        A1[0].w[0] = v0[0]; A1[0].w[1] = v0[1];
        A1[1].w[0] = v0[2]; A1[1].w[1] = v0[3];
        A1[2].w[0] = v1[0]; A1[2].w[1] = v1[1];
        A1[3].w[0] = v1[2]; A1[3].w[1] = v1[3];
    }
    H4 A2m0[4], A2m1[4];
    {
        u32x4 v0 = tab[2 * 64 + lane];
        u32x4 v1 = tab[3 * 64 + lane];
        u32x4 v2 = tab[4 * 64 + lane];
        u32x4 v3 = tab[5 * 64 + lane];
        A2m0[0].w[0] = v0[0]; A2m0[0].w[1] = v0[1];
        A2m0[1].w[0] = v0[2]; A2m0[1].w[1] = v0[3];
        A2m0[2].w[0] = v1[0]; A2m0[2].w[1] = v1[1];
        A2m0[3].w[0] = v1[2]; A2m0[3].w[1] = v1[3];
        A2m1[0].w[0] = v2[0]; A2m1[0].w[1] = v2[1];
        A2m1[1].w[0] = v2[2]; A2m1[1].w[1] = v2[3];
        A2m1[2].w[0] = v3[0]; A2m1[2].w[1] = v3[1];
        A2m1[3].w[0] = v3[2]; A2m1[3].w[1] = v3[3];
    }
    const f32x4 accInit0 = __builtin_bit_cast(f32x4, tab[6 * 64 + lane]);
    const f32x4 accInit1 = __builtin_bit_cast(f32x4, tab[7 * 64 + lane]);
    h2 w3p[4];
    {
        u32x4 v = tab[8 * 64 + lane];
        #pragma unroll
        for (int e = 0; e < 4; ++e)
            w3p[e] = __builtin_bit_cast(h2, (unsigned int)v[e]);
    }

    h2 zeroh; zeroh[0] = (_Float16)0.f; zeroh[1] = (_Float16)0.f;
    h2 one0;  one0[0]  = (_Float16)1.f; one0[1]  = (_Float16)0.f;
    const f32x4 zero4 = {0.f, 0.f, 0.f, 0.f};

    const int seg = wv * 128;

    #pragma unroll
    for (int r = 0; r < 2; ++r) {
        const float2* P = (const float2*)(wp + (size_t)(row0 + r) * NPT * 2);

        #pragma unroll
        for (int s = 0; s < 2; ++s) {
            const int base = seg + s * 64;
            const int g    = base + lane;

            // ---- features for THIS lane's point, computed once (verified) ----
            float2 p  = P[g];
            float2 pm = P[(g > 0) ? g - 1 : 0];
            float2 pp = P[(g < NPT - 1) ? g + 1 : NPT - 1];
            float d1x, d1y;
            if (g < NPT - 1) { d1x = pp.x - p.x; d1y = pp.y - p.y; }
            else             { d1x = p.x - pm.x; d1y = p.y - pm.y; }
            float d2x = 0.f, d2y = 0.f;
            if (g >= 1 && g <= NPT - 2) {
                d2x = pp.x - 2.f * p.x + pm.x;
                d2y = pp.y - 2.f * p.y + pm.y;
            }
            h2 f01 = pkrtz(d1x, d1y);
            h2 f23 = pkrtz(d2x, d2y);
            const int u01 = __builtin_bit_cast(int, f01);
            const int u23 = __builtin_bit_cast(int, f23);

            float vkeep = 0.f;

            #pragma unroll
            for (int q = 0; q < 4; ++q) {
                // features of point base + q*16 + nn from its owner lane
                h2 r01 = __builtin_bit_cast(h2, __shfl(u01, q * 16 + nn));
                h2 r23 = __builtin_bit_cast(h2, __shfl(u23, q * 16 + nn));

                // B1: k0-3 = features (kg==0), k4 = 1.0 (kg==1, bias), else 0
                H4 B1;
                B1.p[0] = (kg == 0) ? r01 : ((kg == 1) ? one0 : zeroh);
                B1.p[1] = (kg == 0) ? r23 : zeroh;

                // layer 1: 4 MFMAs, D = preact; lane holds chs t*16+kg*4+r of pt nn
                f32x4 d0 = mfma16(A1[0].v, B1.v, zero4);
                f32x4 d1 = mfma16(A1[1].v, B1.v, zero4);
                f32x4 d2 = mfma16(A1[2].v, B1.v, zero4);
                f32x4 d3 = mfma16(A1[3].v, B1.v, zero4);

                // relu + pack -> layer-2 B fragments (layout identity, no shfl)
                H4 B2[4];
                B2[0].p[0] = pkrtz(fmaxf(d0[0], 0.f), fmaxf(d0[1], 0.f));
                B2[0].p[1] = pkrtz(fmaxf(d0[2], 0.f), fmaxf(d0[3], 0.f));
                B2[1].p[0] = pkrtz(fmaxf(d1[0], 0.f), fmaxf(d1[1], 0.f));
                B2[1].p[1] = pkrtz(fmaxf(d1[2], 0.f), fmaxf(d1[3], 0.f));
                B2[2].p[0] = pkrtz(fmaxf(d2[0], 0.f), fmaxf(d2[1], 0.f));
                B2[2].p[1] = pkrtz(fmaxf(d2[2], 0.f), fmaxf(d2[3], 0.f));
                B2[3].p[0] = pkrtz(fmaxf(d3[0], 0.f), fmaxf(d3[1], 0.f));
                B2[3].p[1] = pkrtz(fmaxf(d3[2], 0.f), fmaxf(d3[3], 0.f));

                // layer 2: 8 MFMAs over 4 K-steps, C init = b2
                f32x4 acc0 = accInit0;
                f32x4 acc1 = accInit1;
                acc0 = mfma16(A2m0[0].v, B2[0].v, acc0);
                acc1 = mfma16(A2m1[0].v, B2[0].v, acc1);
                acc0 = mfma16(A2m0[1].v, B2[1].v, acc0);
                acc1 = mfma16(A2m1[1].v, B2[1].v, acc1);
                acc0 = mfma16(A2m0[2].v, B2[2].v, acc0);
                acc1 = mfma16(A2m1[2].v, B2[2].v, acc1);
                acc0 = mfma16(A2m0[3].v, B2[3].v, acc0);
                acc1 = mfma16(A2m1[3].v, B2[3].v, acc1);

                // layer 3 (round-10 verified): pack->relu->dot2, 2 shfl_xor
                h2 p0 = __builtin_elementwise_max(pkrtz(acc0[0], acc0[1]), zeroh);
                h2 p1 = __builtin_elementwise_max(pkrtz(acc0[2], acc0[3]), zeroh);
                h2 p2 = __builtin_elementwise_max(pkrtz(acc1[0], acc1[1]), zeroh);
                h2 p3 = __builtin_elementwise_max(pkrtz(acc1[2], acc1[3]), zeroh);
                float v = fdot2(p0, w3p[0], 0.f);
                v = fdot2(p1, w3p[1], v);
                v = fdot2(p2, w3p[2], v);
                v = fdot2(p3, w3p[3], v);
                v += __shfl_xor(v, 16);
                v += __shfl_xor(v, 32);
                vkeep = (q == kg) ? v : vkeep;
            }

            sLg[r][g] = vkeep;   // contiguous LDS store
        }
    }

    __syncthreads();

    // ---- scan: 4 waves = 2 rows x 2 half-scans with prefix fixup (verified) ----
    {
        const int rloc = wv >> 1;        // row within block
        const int half = wv & 1;         // 0: pts 0-255, 1: pts 256-511
        const int row  = row0 + rloc;
        const float2* P = (const float2*)(wp + (size_t)row * NPT * 2);
        const float bias3 = b3[0];
        const float swv   = sigmoidf_fast(sww[0]);

        const int base = half * 256 + lane * 4;   // 4 points per lane
        float wr[4];
        *reinterpret_cast<float4*>(&wr[0]) =
            *reinterpret_cast<const float4*>(&sLg[rloc][base]);

        const float4* P4 = (const float4*)P;
        float2 pts[4];
        #pragma unroll
        for (int s = 0; s < 2; ++s) {
            float4 v = P4[base / 2 + s];
            pts[2 * s].x     = v.x; pts[2 * s].y     = v.y;
            pts[2 * s + 1].x = v.z; pts[2 * s + 1].y = v.w;
        }

        float a4[4], cx4[4], cy4[4];
        float A = 1.f, Cx = 0.f, Cy = 0.f;
        #pragma unroll
        for (int i = 0; i < 4; ++i) {
            const int g = base + i;
            float a = (g == 0) ? 0.f
                               : swv * (1.f - sigmoidf_fast(wr[i] + bias3));
            float cx = (1.f - a) * pts[i].x;
            float cy = (1.f - a) * pts[i].y;
            a4[i] = a; cx4[i] = cx; cy4[i] = cy;
            Cx = fmaf(a, Cx, cx);
            Cy = fmaf(a, Cy, cy);
            A *= a;
        }
        #pragma unroll
        for (int d = 1; d < 64; d <<= 1) {
            float Ap  = __shfl_up(A, d);
            float Cpx = __shfl_up(Cx, d);
            float Cpy = __shfl_up(Cy, d);
            if (lane >= d) {
                Cx = fmaf(A, Cpx, Cx);
                Cy = fmaf(A, Cpy, Cy);
                A *= Ap;
            }
        }
        // exclusive per-lane prefix (within this half)
        float Aex  = __shfl_up(A, 1);
        float Cxex = __shfl_up(Cx, 1);
        float Cyex = __shfl_up(Cy, 1);

        float4* orow = (float4*)(out + (size_t)row * NPT * 2);

        if (half == 0) {
            float yx = (lane == 0) ? 0.f : Cxex;
            float yy = (lane == 0) ? 0.f : Cyex;
            float ox[4], oy[4];
            #pragma unroll
            for (int i = 0; i < 4; ++i) {
                yx = fmaf(a4[i], yx, cx4[i]);
                yy = fmaf(a4[i], yy, cy4[i]);
                ox[i] = yx; oy[i] = yy;
            }
            orow[base / 2]     = make_float4(ox[0], oy[0], ox[1], oy[1]);
            orow[base / 2 + 1] = make_float4(ox[2], oy[2], ox[3], oy[3]);
            if (lane == 63) { sY[rloc].x = yx; sY[rloc].y = yy; }  // y_255
        }

        __syncthreads();

        if (half == 1) {
            const float2 y255 = sY[rloc];
            float yx = (lane == 0) ? y255.x : fmaf(Aex, y255.x, Cxex);
            float yy = (lane == 0) ? y255.y : fmaf(Aex, y255.y, Cyex);
            float ox[4], oy[4];
            #pragma unroll
            for (int i = 0; i < 4; ++i) {
                yx = fmaf(a4[i], yx, cx4[i]);
                yy = fmaf(a4[i], yy, cy4[i]);
                ox[i] = yx; oy[i] = yy;
            }
            if (lane == 63) {                 // pin endpoint to original
                float2 pe = P[NPT - 1];
                ox[3] = pe.x; oy[3] = pe.y;
            }
            orow[base / 2]     = make_float4(ox[0], oy[0], ox[1], oy[1]);
            orow[base / 2 + 1] = make_float4(ox[2], oy[2], ox[3], oy[3]);
        }
    }
}

extern "C" void kernel_launch(void* const* d_in, const int* in_sizes, int n_in,
                              void* d_out, int out_size, void* d_ws, size_t ws_size,
                              hipStream_t stream) {
    const float* wp  = (const float*)d_in[0];
    const float* sww = (const float*)d_in[1];
    const float* W1  = (const float*)d_in[2];
    const float* b1  = (const float*)d_in[3];
    const float* W2  = (const float*)d_in[4];
    const float* b2  = (const float*)d_in[5];
    const float* W3  = (const float*)d_in[6];
    const float* b3  = (const float*)d_in[7];
    float* out = (float*)d_out;
    u32x4* tab = (u32x4*)d_ws;   // 9.2 KB used; ws is far larger

    setup_kernel<<<1, 64, 0, stream>>>(W1, b1, W2, b2, W3, tab);
    wps_kernel<<<BROWS / 2, 256, 0, stream>>>(wp, sww, b3, tab, out);
}

// Round 12
// 31.466 us; speedup vs baseline: 1.1285x; 1.1285x over previous
//
#include <hip/hip_runtime.h>
#include <math.h>

#define NPT 512
#define BROWS 4096
#define TAB_U4 10   // 10 uint4 slots per lane, SoA: tab[slot*64 + lane]

typedef _Float16 half8  __attribute__((ext_vector_type(8)));
typedef _Float16 h2     __attribute__((ext_vector_type(2)));
typedef float    f32x16 __attribute__((ext_vector_type(16)));
typedef unsigned int u32x4 __attribute__((ext_vector_type(4)));

__device__ __forceinline__ float sigmoidf_fast(float x) {
    return 1.0f / (1.0f + __expf(-x));
}

__device__ __forceinline__ h2 pkrtz(float a, float b) {
    return __builtin_bit_cast(h2, __builtin_amdgcn_cvt_pkrtz(a, b));
}

#if __has_builtin(__builtin_amdgcn_fdot2)
__device__ __forceinline__ float fdot2(h2 a, h2 b, float c) {
    return __builtin_amdgcn_fdot2(__builtin_bit_cast(__fp16 __attribute__((ext_vector_type(2))), a),
                                  __builtin_bit_cast(__fp16 __attribute__((ext_vector_type(2))), b),
                                  c, false);
}
#else
__device__ __forceinline__ float fdot2(h2 a, h2 b, float c) {
    c = fmaf((float)a[0], (float)b[0], c);
    c = fmaf((float)a[1], (float)b[1], c);
    return c;
}
#endif

union H8 { half8 v; h2 p[4]; unsigned int w[4]; };

__device__ __forceinline__ f32x16 mfma32(half8 a, half8 b, f32x16 c) {
    return __builtin_amdgcn_mfma_f32_32x32x16_f16(a, b, c, 0, 0, 0);
}

// v_permlane32_swap_b32: a[32..63] <-> b[0..31].
// Post: a = {a_lo, b_lo-from-partner}, b = {a_hi-from-partner, b_hi}.
__device__ __forceinline__ void pl32swap(unsigned &a, unsigned &b) {
    asm volatile("v_permlane32_swap_b32 %0, %1" : "+v"(a), "+v"(b));
}

// Build one 16-ch-window B fragment from 4 packed row-pair words.
// p0={r0,r1} p1={r2,r3} p2={r8,r9} p3={r10,r11} (+4*hi on hi lanes).
// After swaps: word0=p0', word1=p1', word2=p2', word3=p3' give k=hi*8+j rows.
__device__ __forceinline__ half8 makeB2(unsigned p0, unsigned p1,
                                        unsigned p2, unsigned p3) {
    pl32swap(p0, p2);
    pl32swap(p1, p3);
    H8 B; B.w[0] = p0; B.w[1] = p1; B.w[2] = p2; B.w[3] = p3;
    return B.v;
}

// ---------------- setup: per-lane constant table (1 wave) ----------------
// slot0-1: A1 tiles (layer1 A = W1^T, bias at k=4; hi lanes zero)
// slot2-5: A2 steps  (layer2 A = W2^T, A2[s][j] = W2[(s*16+hi*8+j)*32 + c])
// slot6-7: b2 packed by D-row pairs; slot8-9: W3 packed by D-row pairs
__global__ __launch_bounds__(64) void setup_kernel(
    const float* __restrict__ W1, const float* __restrict__ b1,
    const float* __restrict__ W2, const float* __restrict__ b2,
    const float* __restrict__ W3, u32x4* __restrict__ tab)
{
    const int lane = threadIdx.x & 63;
    const int c    = lane & 31;
    const int hi   = lane >> 5;

    #pragma unroll
    for (int t = 0; t < 2; ++t) {
        H8 a;
        a.w[0] = 0u; a.w[1] = 0u; a.w[2] = 0u; a.w[3] = 0u;
        if (hi == 0) {
            const int ch = t * 32 + c;
            h2 v0; v0[0] = (_Float16)W1[0 * 64 + ch]; v0[1] = (_Float16)W1[1 * 64 + ch];
            h2 v1; v1[0] = (_Float16)W1[2 * 64 + ch]; v1[1] = (_Float16)W1[3 * 64 + ch];
            h2 v2; v2[0] = (_Float16)b1[ch];          v2[1] = (_Float16)0.f;
            a.p[0] = v0; a.p[1] = v1; a.p[2] = v2;
        }
        u32x4 o; o[0] = a.w[0]; o[1] = a.w[1]; o[2] = a.w[2]; o[3] = a.w[3];
        tab[t * 64 + lane] = o;
    }

    #pragma unroll
    for (int s = 0; s < 4; ++s) {
        H8 a;
        #pragma unroll
        for (int jj = 0; jj < 4; ++jj) {
            const int k = s * 16 + hi * 8 + 2 * jj;
            h2 v; v[0] = (_Float16)W2[k * 32 + c]; v[1] = (_Float16)W2[(k + 1) * 32 + c];
            a.p[jj] = v;
        }
        u32x4 o; o[0] = a.w[0]; o[1] = a.w[1]; o[2] = a.w[2]; o[3] = a.w[3];
        tab[(2 + s) * 64 + lane] = o;
    }

    unsigned bw[8], ww[8];
    #pragma unroll
    for (int rr = 0; rr < 8; ++rr) {
        const int q   = 2 * rr;
        const int row = (q & 3) + 8 * (q >> 2) + 4 * hi;
        h2 bv; bv[0] = (_Float16)b2[row]; bv[1] = (_Float16)b2[row + 1];
        h2 wv; wv[0] = (_Float16)W3[row]; wv[1] = (_Float16)W3[row + 1];
        bw[rr] = __builtin_bit_cast(unsigned, bv);
        ww[rr] = __builtin_bit_cast(unsigned, wv);
    }
    {
        u32x4 o0, o1, o2, o3;
        #pragma unroll
        for (int e = 0; e < 4; ++e) {
            o0[e] = bw[e]; o1[e] = bw[4 + e];
            o2[e] = ww[e]; o3[e] = ww[4 + e];
        }
        tab[6 * 64 + lane] = o0;
        tab[7 * 64 + lane] = o1;
        tab[8 * 64 + lane] = o2;
        tab[9 * 64 + lane] = o3;
    }
}

// ---------------- main: 1 block = 2 rows = 4 waves ----------------
// MLP on 32x32x16 MFMA: L1 = 2 MFMA (bias in K), permlane32_swap repack,
// L2 = 4 MFMA (all 32 out-ch in one tile), epilogue dot2 + 1 shfl_xor.
// Scan: round-10 verified split-scan.
__global__ __launch_bounds__(256, 5) void wps_kernel(
    const float* __restrict__ wp,    // (B, N, 2)
    const float* __restrict__ sww,
    const float* __restrict__ b3,
    const u32x4* __restrict__ tab,
    float* __restrict__ out)
{
    __shared__ float sLg[2][NPT];    // raw logits, 4 KB
    __shared__ float2 sY[2];         // y_255 per row

    const int t    = threadIdx.x;
    const int lane = t & 63;
    const int wv   = t >> 6;
    const int row0 = blockIdx.x * 2;
    const int c    = lane & 31;

    // ---- constants (10 coalesced dwordx4 loads, ~40 VGPR) ----
    half8 A1t[2];
    #pragma unroll
    for (int i = 0; i < 2; ++i) {
        u32x4 v = tab[i * 64 + lane];
        H8 a; a.w[0] = v[0]; a.w[1] = v[1]; a.w[2] = v[2]; a.w[3] = v[3];
        A1t[i] = a.v;
    }
    half8 A2s[4];
    #pragma unroll
    for (int i = 0; i < 4; ++i) {
        u32x4 v = tab[(2 + i) * 64 + lane];
        H8 a; a.w[0] = v[0]; a.w[1] = v[1]; a.w[2] = v[2]; a.w[3] = v[3];
        A2s[i] = a.v;
    }
    h2 b2p[8], w3p[8];
    {
        u32x4 v0 = tab[6 * 64 + lane];
        u32x4 v1 = tab[7 * 64 + lane];
        u32x4 v2 = tab[8 * 64 + lane];
        u32x4 v3 = tab[9 * 64 + lane];
        #pragma unroll
        for (int e = 0; e < 4; ++e) {
            b2p[e]     = __builtin_bit_cast(h2, (unsigned)v0[e]);
            b2p[4 + e] = __builtin_bit_cast(h2, (unsigned)v1[e]);
            w3p[e]     = __builtin_bit_cast(h2, (unsigned)v2[e]);
            w3p[4 + e] = __builtin_bit_cast(h2, (unsigned)v3[e]);
        }
    }

    h2 zeroh; zeroh[0] = (_Float16)0.f; zeroh[1] = (_Float16)0.f;
    const f32x16 zero16 = {0.f,0.f,0.f,0.f,0.f,0.f,0.f,0.f,
                           0.f,0.f,0.f,0.f,0.f,0.f,0.f,0.f};

    const int seg = wv * 128;

    #pragma unroll
    for (int r = 0; r < 2; ++r) {
        const float2* P = (const float2*)(wp + (size_t)(row0 + r) * NPT * 2);

        #pragma unroll
        for (int s2 = 0; s2 < 2; ++s2) {
            const int base = seg + s2 * 64;
            const int g    = base + lane;

            // features for THIS lane's point, computed once (verified)
            float2 p  = P[g];
            float2 pm = P[(g > 0) ? g - 1 : 0];
            float2 pp = P[(g < NPT - 1) ? g + 1 : NPT - 1];
            float d1x, d1y;
            if (g < NPT - 1) { d1x = pp.x - p.x; d1y = pp.y - p.y; }
            else             { d1x = p.x - pm.x; d1y = p.y - pm.y; }
            float d2x = 0.f, d2y = 0.f;
            if (g >= 1 && g <= NPT - 2) {
                d2x = pp.x - 2.f * p.x + pm.x;
                d2y = pp.y - 2.f * p.y + pm.y;
            }
            const int u01 = __builtin_bit_cast(int, pkrtz(d1x, d1y));
            const int u23 = __builtin_bit_cast(int, pkrtz(d2x, d2y));

            #pragma unroll
            for (int T = 0; T < 2; ++T) {
                // features of point base + T*32 + c from its owner lane
                const unsigned r01 = (unsigned)__shfl(u01, T * 32 + c);
                const unsigned r23 = (unsigned)__shfl(u23, T * 32 + c);
                // B1: k0-3 = features, k4 = 1.0 (bias), k5-7 = 0;
                // hi-lane contents multiply A1's zeroed hi rows -> don't care.
                H8 B1;
                B1.w[0] = r01; B1.w[1] = r23;
                B1.w[2] = 0x00003C00u; B1.w[3] = 0u;

                // layer 1: 2 MFMAs -> 64 pre-act channels (f32, bias folded)
                f32x16 pre0 = mfma32(A1t[0], B1.v, zero16);
                f32x16 pre1 = mfma32(A1t[1], B1.v, zero16);

                // relu + pack row pairs
                unsigned pw0[8], pw1[8];
                #pragma unroll
                for (int rr = 0; rr < 8; ++rr) {
                    pw0[rr] = __builtin_bit_cast(unsigned,
                        __builtin_elementwise_max(pkrtz(pre0[2*rr], pre0[2*rr+1]), zeroh));
                    pw1[rr] = __builtin_bit_cast(unsigned,
                        __builtin_elementwise_max(pkrtz(pre1[2*rr], pre1[2*rr+1]), zeroh));
                }

                // layer 2: 4 MFMAs over 4 K-steps (permlane repack, no DS)
                f32x16 acc = zero16;
                acc = mfma32(A2s[0], makeB2(pw0[0], pw0[1], pw0[2], pw0[3]), acc);
                acc = mfma32(A2s[1], makeB2(pw0[4], pw0[5], pw0[6], pw0[7]), acc);
                acc = mfma32(A2s[2], makeB2(pw1[0], pw1[1], pw1[2], pw1[3]), acc);
                acc = mfma32(A2s[3], makeB2(pw1[4], pw1[5], pw1[6], pw1[7]), acc);

                // layer 3: +b2, relu, dot with W3 over this lane's 16 rows,
                // partner lane holds the other 16 -> one shfl_xor(32)
                float v = 0.f;
                #pragma unroll
                for (int rr = 0; rr < 8; ++rr) {
                    h2 tt = pkrtz(acc[2*rr], acc[2*rr+1]);
                    tt = tt + b2p[rr];
                    tt = __builtin_elementwise_max(tt, zeroh);
                    v = fdot2(tt, w3p[rr], v);
                }
                v += __shfl_xor(v, 32);
                if (lane < 32) sLg[r][base + T * 32 + lane] = v;
            }
        }
    }

    __syncthreads();

    // ---- scan: 4 waves = 2 rows x 2 half-scans with prefix fixup (verified) ----
    {
        const int rloc = wv >> 1;
        const int half = wv & 1;
        const int row  = row0 + rloc;
        const float2* P = (const float2*)(wp + (size_t)row * NPT * 2);
        const float bias3 = b3[0];
        const float swv   = sigmoidf_fast(sww[0]);

        const int base = half * 256 + lane * 4;
        float wr[4];
        *reinterpret_cast<float4*>(&wr[0]) =
            *reinterpret_cast<const float4*>(&sLg[rloc][base]);

        const float4* P4 = (const float4*)P;
        float2 pts[4];
        #pragma unroll
        for (int s = 0; s < 2; ++s) {
            float4 v = P4[base / 2 + s];
            pts[2 * s].x     = v.x; pts[2 * s].y     = v.y;
            pts[2 * s + 1].x = v.z; pts[2 * s + 1].y = v.w;
        }

        float a4[4], cx4[4], cy4[4];
        float A = 1.f, Cx = 0.f, Cy = 0.f;
        #pragma unroll
        for (int i = 0; i < 4; ++i) {
            const int g = base + i;
            float a = (g == 0) ? 0.f
                               : swv * (1.f - sigmoidf_fast(wr[i] + bias3));
            float cx = (1.f - a) * pts[i].x;
            float cy = (1.f - a) * pts[i].y;
            a4[i] = a; cx4[i] = cx; cy4[i] = cy;
            Cx = fmaf(a, Cx, cx);
            Cy = fmaf(a, Cy, cy);
            A *= a;
        }
        #pragma unroll
        for (int d = 1; d < 64; d <<= 1) {
            float Ap  = __shfl_up(A, d);
            float Cpx = __shfl_up(Cx, d);
            float Cpy = __shfl_up(Cy, d);
            if (lane >= d) {
                Cx = fmaf(A, Cpx, Cx);
                Cy = fmaf(A, Cpy, Cy);
                A *= Ap;
            }
        }
        float Aex  = __shfl_up(A, 1);
        float Cxex = __shfl_up(Cx, 1);
        float Cyex = __shfl_up(Cy, 1);

        float4* orow = (float4*)(out + (size_t)row * NPT * 2);

        if (half == 0) {
            float yx = (lane == 0) ? 0.f : Cxex;
            float yy = (lane == 0) ? 0.f : Cyex;
            float ox[4], oy[4];
            #pragma unroll
            for (int i = 0; i < 4; ++i) {
                yx = fmaf(a4[i], yx, cx4[i]);
                yy = fmaf(a4[i], yy, cy4[i]);
                ox[i] = yx; oy[i] = yy;
            }
            orow[base / 2]     = make_float4(ox[0], oy[0], ox[1], oy[1]);
            orow[base / 2 + 1] = make_float4(ox[2], oy[2], ox[3], oy[3]);
            if (lane == 63) { sY[rloc].x = yx; sY[rloc].y = yy; }
        }

        __syncthreads();

        if (half == 1) {
            const float2 y255 = sY[rloc];
            float yx = (lane == 0) ? y255.x : fmaf(Aex, y255.x, Cxex);
            float yy = (lane == 0) ? y255.y : fmaf(Aex, y255.y, Cyex);
            float ox[4], oy[4];
            #pragma unroll
            for (int i = 0; i < 4; ++i) {
                yx = fmaf(a4[i], yx, cx4[i]);
                yy = fmaf(a4[i], yy, cy4[i]);
                ox[i] = yx; oy[i] = yy;
            }
            if (lane == 63) {
                float2 pe = P[NPT - 1];
                ox[3] = pe.x; oy[3] = pe.y;
            }
            orow[base / 2]     = make_float4(ox[0], oy[0], ox[1], oy[1]);
            orow[base / 2 + 1] = make_float4(ox[2], oy[2], ox[3], oy[3]);
        }
    }
}

extern "C" void kernel_launch(void* const* d_in, const int* in_sizes, int n_in,
                              void* d_out, int out_size, void* d_ws, size_t ws_size,
                              hipStream_t stream) {
    const float* wp  = (const float*)d_in[0];
    const float* sww = (const float*)d_in[1];
    const float* W1  = (const float*)d_in[2];
    const float* b1  = (const float*)d_in[3];
    const float* W2  = (const float*)d_in[4];
    const float* b2  = (const float*)d_in[5];
    const float* W3  = (const float*)d_in[6];
    const float* b3  = (const float*)d_in[7];
    float* out = (float*)d_out;
    u32x4* tab = (u32x4*)d_ws;   // 10 KB used; ws is far larger

    setup_kernel<<<1, 64, 0, stream>>>(W1, b1, W2, b2, W3, tab);
    wps_kernel<<<BROWS / 2, 256, 0, stream>>>(wp, sww, b3, tab, out);
}

// Round 13
// 27.608 us; speedup vs baseline: 1.2862x; 1.1397x over previous
//
#include <hip/hip_runtime.h>
#include <math.h>

#define NPT 512
#define BROWS 4096

typedef _Float16 half8  __attribute__((ext_vector_type(8)));
typedef _Float16 h2     __attribute__((ext_vector_type(2)));
typedef float    f32x16 __attribute__((ext_vector_type(16)));

__device__ __forceinline__ float sigmoidf_fast(float x) {
    return 1.0f / (1.0f + __expf(-x));
}

__device__ __forceinline__ h2 pkrtz(float a, float b) {
    return __builtin_bit_cast(h2, __builtin_amdgcn_cvt_pkrtz(a, b));
}

#if __has_builtin(__builtin_amdgcn_fdot2)
__device__ __forceinline__ float fdot2(h2 a, h2 b, float c) {
    return __builtin_amdgcn_fdot2(__builtin_bit_cast(__fp16 __attribute__((ext_vector_type(2))), a),
                                  __builtin_bit_cast(__fp16 __attribute__((ext_vector_type(2))), b),
                                  c, false);
}
#else
__device__ __forceinline__ float fdot2(h2 a, h2 b, float c) {
    c = fmaf((float)a[0], (float)b[0], c);
    c = fmaf((float)a[1], (float)b[1], c);
    return c;
}
#endif

union H8 { half8 v; h2 p[4]; unsigned int w[4]; };

__device__ __forceinline__ f32x16 mfma32(half8 a, half8 b, f32x16 c) {
    return __builtin_amdgcn_mfma_f32_32x32x16_f16(a, b, c, 0, 0, 0);
}

// v_permlane32_swap_b32: a[32..63] <-> b[0..31]. (verified round 12)
__device__ __forceinline__ void pl32swap(unsigned &a, unsigned &b) {
    asm volatile("v_permlane32_swap_b32 %0, %1" : "+v"(a), "+v"(b));
}

// Build one 16-ch-window B fragment from 4 packed row-pair words (verified).
__device__ __forceinline__ half8 makeB2(unsigned p0, unsigned p1,
                                        unsigned p2, unsigned p3) {
    pl32swap(p0, p2);
    pl32swap(p1, p3);
    H8 B; B.w[0] = p0; B.w[1] = p1; B.w[2] = p2; B.w[3] = p3;
    return B.v;
}

// ---------------- single fused kernel: 1 block = 2 rows = 4 waves ----------------
// Constants built inline per wave (~40 VGPR, ~26 L2-hit gathers; weights are
// 9 KB -> L2-resident). MLP on 32x32x16 MFMA (round-12 verified layouts):
// L1 = 2 MFMA (bias in K), permlane repack, L2 = 2x2 independent MFMA chains.
// Scan: round-10 verified split-scan.
__global__ __launch_bounds__(256, 4) void wps_kernel(
    const float* __restrict__ wp,    // (B, N, 2)
    const float* __restrict__ sww,
    const float* __restrict__ W1,    // (4, 64)
    const float* __restrict__ b1,    // (64,)
    const float* __restrict__ W2,    // (64, 32)
    const float* __restrict__ b2,    // (32,)
    const float* __restrict__ W3,    // (32, 1)
    const float* __restrict__ b3,    // (1,)
    float* __restrict__ out)
{
    __shared__ float sLg[2][NPT];    // raw logits, 4 KB
    __shared__ float2 sY[2];         // y_255 per row

    const int t    = threadIdx.x;
    const int lane = t & 63;
    const int wv   = t >> 6;
    const int row0 = blockIdx.x * 2;
    const int c    = lane & 31;
    const int hi   = lane >> 5;

    // ---- constants built inline (round-12 verified mappings) ----
    half8 A1t[2];
    #pragma unroll
    for (int tt = 0; tt < 2; ++tt) {
        H8 a;
        a.w[0] = 0u; a.w[1] = 0u; a.w[2] = 0u; a.w[3] = 0u;
        if (hi == 0) {
            const int ch = tt * 32 + c;
            h2 v0; v0[0] = (_Float16)W1[0 * 64 + ch]; v0[1] = (_Float16)W1[1 * 64 + ch];
            h2 v1; v1[0] = (_Float16)W1[2 * 64 + ch]; v1[1] = (_Float16)W1[3 * 64 + ch];
            h2 v2; v2[0] = (_Float16)b1[ch];          v2[1] = (_Float16)0.f;
            a.p[0] = v0; a.p[1] = v1; a.p[2] = v2;
        }
        A1t[tt] = a.v;
    }
    half8 A2s[4];
    #pragma unroll
    for (int s = 0; s < 4; ++s) {
        H8 a;
        #pragma unroll
        for (int jj = 0; jj < 4; ++jj) {
            const int k = s * 16 + hi * 8 + 2 * jj;
            h2 v; v[0] = (_Float16)W2[k * 32 + c]; v[1] = (_Float16)W2[(k + 1) * 32 + c];
            a.p[jj] = v;
        }
        A2s[s] = a.v;
    }
    h2 b2p[8], w3p[8];
    #pragma unroll
    for (int rr = 0; rr < 8; ++rr) {
        const int q   = 2 * rr;
        const int row = (q & 3) + 8 * (q >> 2) + 4 * hi;
        h2 bv; bv[0] = (_Float16)b2[row]; bv[1] = (_Float16)b2[row + 1];
        h2 wv2; wv2[0] = (_Float16)W3[row]; wv2[1] = (_Float16)W3[row + 1];
        b2p[rr] = bv;
        w3p[rr] = wv2;
    }

    h2 zeroh; zeroh[0] = (_Float16)0.f; zeroh[1] = (_Float16)0.f;
    const f32x16 zero16 = {0.f,0.f,0.f,0.f,0.f,0.f,0.f,0.f,
                           0.f,0.f,0.f,0.f,0.f,0.f,0.f,0.f};

    const int seg = wv * 128;

    #pragma unroll
    for (int r = 0; r < 2; ++r) {
        const float2* P = (const float2*)(wp + (size_t)(row0 + r) * NPT * 2);

        #pragma unroll
        for (int s2 = 0; s2 < 2; ++s2) {
            const int base = seg + s2 * 64;
            const int g    = base + lane;

            // features for THIS lane's point, computed once (verified)
            float2 p  = P[g];
            float2 pm = P[(g > 0) ? g - 1 : 0];
            float2 pp = P[(g < NPT - 1) ? g + 1 : NPT - 1];
            float d1x, d1y;
            if (g < NPT - 1) { d1x = pp.x - p.x; d1y = pp.y - p.y; }
            else             { d1x = p.x - pm.x; d1y = p.y - pm.y; }
            float d2x = 0.f, d2y = 0.f;
            if (g >= 1 && g <= NPT - 2) {
                d2x = pp.x - 2.f * p.x + pm.x;
                d2y = pp.y - 2.f * p.y + pm.y;
            }
            const int u01 = __builtin_bit_cast(int, pkrtz(d1x, d1y));
            const int u23 = __builtin_bit_cast(int, pkrtz(d2x, d2y));

            #pragma unroll
            for (int T = 0; T < 2; ++T) {
                // features of point base + T*32 + c from its owner lane
                const unsigned r01 = (unsigned)__shfl(u01, T * 32 + c);
                const unsigned r23 = (unsigned)__shfl(u23, T * 32 + c);
                // B1: k0-3 = features, k4 = 1.0 (bias), k5-7 = 0 (verified)
                H8 B1;
                B1.w[0] = r01; B1.w[1] = r23;
                B1.w[2] = 0x00003C00u; B1.w[3] = 0u;

                // layer 1: 2 MFMAs -> 64 pre-act channels (bias folded)
                f32x16 pre0 = mfma32(A1t[0], B1.v, zero16);
                f32x16 pre1 = mfma32(A1t[1], B1.v, zero16);

                // relu + pack row pairs
                unsigned pw0[8], pw1[8];
                #pragma unroll
                for (int rr = 0; rr < 8; ++rr) {
                    pw0[rr] = __builtin_bit_cast(unsigned,
                        __builtin_elementwise_max(pkrtz(pre0[2*rr], pre0[2*rr+1]), zeroh));
                    pw1[rr] = __builtin_bit_cast(unsigned,
                        __builtin_elementwise_max(pkrtz(pre1[2*rr], pre1[2*rr+1]), zeroh));
                }

                // layer 2: two INDEPENDENT 2-deep MFMA chains (halved dep latency)
                f32x16 accA = zero16;
                f32x16 accB = zero16;
                accA = mfma32(A2s[0], makeB2(pw0[0], pw0[1], pw0[2], pw0[3]), accA);
                accB = mfma32(A2s[1], makeB2(pw0[4], pw0[5], pw0[6], pw0[7]), accB);
                accA = mfma32(A2s[2], makeB2(pw1[0], pw1[1], pw1[2], pw1[3]), accA);
                accB = mfma32(A2s[3], makeB2(pw1[4], pw1[5], pw1[6], pw1[7]), accB);

                // layer 3: +b2, relu, dot with W3; partner holds other 16 rows
                float v = 0.f;
                #pragma unroll
                for (int rr = 0; rr < 8; ++rr) {
                    h2 tt2 = pkrtz(accA[2*rr] + accB[2*rr],
                                   accA[2*rr+1] + accB[2*rr+1]);
                    tt2 = tt2 + b2p[rr];
                    tt2 = __builtin_elementwise_max(tt2, zeroh);
                    v = fdot2(tt2, w3p[rr], v);
                }
                v += __shfl_xor(v, 32);
                if (lane < 32) sLg[r][base + T * 32 + lane] = v;
            }
        }
    }

    __syncthreads();

    // ---- scan: 4 waves = 2 rows x 2 half-scans with prefix fixup (verified) ----
    {
        const int rloc = wv >> 1;
        const int half = wv & 1;
        const int row  = row0 + rloc;
        const float2* P = (const float2*)(wp + (size_t)row * NPT * 2);
        const float bias3 = b3[0];
        const float swv   = sigmoidf_fast(sww[0]);

        const int base = half * 256 + lane * 4;
        float wr[4];
        *reinterpret_cast<float4*>(&wr[0]) =
            *reinterpret_cast<const float4*>(&sLg[rloc][base]);

        const float4* P4 = (const float4*)P;
        float2 pts[4];
        #pragma unroll
        for (int s = 0; s < 2; ++s) {
            float4 v = P4[base / 2 + s];
            pts[2 * s].x     = v.x; pts[2 * s].y     = v.y;
            pts[2 * s + 1].x = v.z; pts[2 * s + 1].y = v.w;
        }

        float a4[4], cx4[4], cy4[4];
        float A = 1.f, Cx = 0.f, Cy = 0.f;
        #pragma unroll
        for (int i = 0; i < 4; ++i) {
            const int g = base + i;
            float a = (g == 0) ? 0.f
                               : swv * (1.f - sigmoidf_fast(wr[i] + bias3));
            float cx = (1.f - a) * pts[i].x;
            float cy = (1.f - a) * pts[i].y;
            a4[i] = a; cx4[i] = cx; cy4[i] = cy;
            Cx = fmaf(a, Cx, cx);
            Cy = fmaf(a, Cy, cy);
            A *= a;
        }
        #pragma unroll
        for (int d = 1; d < 64; d <<= 1) {
            float Ap  = __shfl_up(A, d);
            float Cpx = __shfl_up(Cx, d);
            float Cpy = __shfl_up(Cy, d);
            if (lane >= d) {
                Cx = fmaf(A, Cpx, Cx);
                Cy = fmaf(A, Cpy, Cy);
                A *= Ap;
            }
        }
        float Aex  = __shfl_up(A, 1);
        float Cxex = __shfl_up(Cx, 1);
        float Cyex = __shfl_up(Cy, 1);

        float4* orow = (float4*)(out + (size_t)row * NPT * 2);

        if (half == 0) {
            float yx = (lane == 0) ? 0.f : Cxex;
            float yy = (lane == 0) ? 0.f : Cyex;
            float ox[4], oy[4];
            #pragma unroll
            for (int i = 0; i < 4; ++i) {
                yx = fmaf(a4[i], yx, cx4[i]);
                yy = fmaf(a4[i], yy, cy4[i]);
                ox[i] = yx; oy[i] = yy;
            }
            orow[base / 2]     = make_float4(ox[0], oy[0], ox[1], oy[1]);
            orow[base / 2 + 1] = make_float4(ox[2], oy[2], ox[3], oy[3]);
            if (lane == 63) { sY[rloc].x = yx; sY[rloc].y = yy; }
        }

        __syncthreads();

        if (half == 1) {
            const float2 y255 = sY[rloc];
            float yx = (lane == 0) ? y255.x : fmaf(Aex, y255.x, Cxex);
            float yy = (lane == 0) ? y255.y : fmaf(Aex, y255.y, Cyex);
            float ox[4], oy[4];
            #pragma unroll
            for (int i = 0; i < 4; ++i) {
                yx = fmaf(a4[i], yx, cx4[i]);
                yy = fmaf(a4[i], yy, cy4[i]);
                ox[i] = yx; oy[i] = yy;
            }
            if (lane == 63) {
                float2 pe = P[NPT - 1];
                ox[3] = pe.x; oy[3] = pe.y;
            }
            orow[base / 2]     = make_float4(ox[0], oy[0], ox[1], oy[1]);
            orow[base / 2 + 1] = make_float4(ox[2], oy[2], ox[3], oy[3]);
        }
    }
}

extern "C" void kernel_launch(void* const* d_in, const int* in_sizes, int n_in,
                              void* d_out, int out_size, void* d_ws, size_t ws_size,
                              hipStream_t stream) {
    const float* wp  = (const float*)d_in[0];
    const float* sww = (const float*)d_in[1];
    const float* W1  = (const float*)d_in[2];
    const float* b1  = (const float*)d_in[3];
    const float* W2  = (const float*)d_in[4];
    const float* b2  = (const float*)d_in[5];
    const float* W3  = (const float*)d_in[6];
    const float* b3  = (const float*)d_in[7];
    float* out = (float*)d_out;

    wps_kernel<<<BROWS / 2, 256, 0, stream>>>(wp, sww, W1, b1, W2, b2, W3, b3, out);
}